// Round 3
// baseline (1821.276 us; speedup 1.0000x reference)
//
#include <hip/hip_runtime.h>

// Problem constants
#define B 2
#define C 192
#define HEADS 6
#define DHEAD 32          // C / HEADS
#define PS 8
#define HW 256
#define HWN 32            // HW / PS
#define NPIX 65536        // HW*HW

// Fully-fused kernel: qkv conv1x1 + dwconv3x3 + windowed channel-attention
// + proj conv1x1. One block per (window, batch), 512 threads.
// ZERO d_ws usage: the block's own 192ch x 64px region of d_out serves as
// scratch for the attention output (exclusive ownership per block; intra-block
// global write->read visibility guaranteed by __syncthreads vmcnt(0)+barrier
// through the same CU's L1).
__global__ __launch_bounds__(512, 2)
void fused_all(const float* __restrict__ x, const float* __restrict__ wqkv,
               const float* __restrict__ wdw, const float* __restrict__ wproj,
               const float* __restrict__ temp, float* __restrict__ out) {
    __shared__ float xh[192][104];   // 79,872 B  x halo (100 cols used, pad->104)
    __shared__ float uni[9984];      // 39,936 B  union: bufW/qkvh/at | bufWp+ot
    __shared__ float qt[32][68];     // 8,704 B   (rows padded to 68 floats)
    __shared__ float kt[32][68];
    __shared__ float vt[32][68];
    __shared__ int   off[100];       // halo px -> plane offset, -1 = zero pad

    const int tid = threadIdx.x;
    const int win = blockIdx.x;
    const int b   = blockIdx.y;
    const int wy = win >> 5, wx = win & 31;
    const int y0 = wy * PS - 1, x0 = wx * PS - 1;

    if (tid < 100) {
        int yy = tid / 10, xx = tid - yy * 10;
        int y = y0 + yy, xg = x0 + xx;
        off[tid] = ((unsigned)y < HW && (unsigned)xg < HW) ? y * HW + xg : -1;
    }
    __syncthreads();

    // ---- stage x halo [192][100] (zero at image border) ----
    const float* xb = x + (size_t)b * C * NPIX;
    for (int f = tid; f < C * 100; f += 512) {
        int ic = f / 100, px = f - ic * 100;
        int o = off[px];
        xh[ic][px] = (o >= 0) ? xb[(size_t)ic * NPIX + o] : 0.f;
    }
    // (first __syncthreads inside the GEMM chunk loop covers this staging)

    const int ocg = tid >> 5;                    // 0..15  (6 oc each = 96)
    const int pxq = tid & 31;                    // halo 4-px group, 25 valid
    const int px4 = (pxq < 25 ? pxq : 24) * 4;   // clamp keeps reads in bounds

    for (int h = 0; h < HEADS; ++h) {
        // ---- per-head qkv GEMM: qkv[96 oc][100 px] = W[96][192] @ xh ----
        float acc[6][4] = {};
        float (*bufW)[32] = (float(*)[32])uni;   // [96 oc][32 kk]
        for (int k0 = 0; k0 < C; k0 += 32) {
            __syncthreads();                      // uni reusable / prev phase done
            #pragma unroll
            for (int i = 0; i < 6; ++i) {
                int f = tid + i * 512;            // 0..3071
                int oc = f >> 5, kk = f & 31;
                int row = (oc >> 5) * C + h * DHEAD + (oc & 31);
                bufW[oc][kk] = wqkv[(size_t)row * C + k0 + kk];
            }
            __syncthreads();
            #pragma unroll
            for (int kk = 0; kk < 32; kk += 4) {
                float4 xv0 = *(float4*)&xh[k0 + kk + 0][px4];
                float4 xv1 = *(float4*)&xh[k0 + kk + 1][px4];
                float4 xv2 = *(float4*)&xh[k0 + kk + 2][px4];
                float4 xv3 = *(float4*)&xh[k0 + kk + 3][px4];
                #pragma unroll
                for (int r = 0; r < 6; ++r) {
                    float4 wv = *(float4*)&bufW[ocg * 6 + r][kk];
                    acc[r][0] += wv.x * xv0.x; acc[r][1] += wv.x * xv0.y;
                    acc[r][2] += wv.x * xv0.z; acc[r][3] += wv.x * xv0.w;
                    acc[r][0] += wv.y * xv1.x; acc[r][1] += wv.y * xv1.y;
                    acc[r][2] += wv.y * xv1.z; acc[r][3] += wv.y * xv1.w;
                    acc[r][0] += wv.z * xv2.x; acc[r][1] += wv.z * xv2.y;
                    acc[r][2] += wv.z * xv2.z; acc[r][3] += wv.z * xv2.w;
                    acc[r][0] += wv.w * xv3.x; acc[r][1] += wv.w * xv3.y;
                    acc[r][2] += wv.w * xv3.z; acc[r][3] += wv.w * xv3.w;
                }
            }
        }
        __syncthreads();                          // all fma done reading bufW

        // ---- dump acc -> qkvh [96][104] (halo layout for dwconv) ----
        float (*qkvh)[104] = (float(*)[104])uni;
        if (pxq < 25) {
            #pragma unroll
            for (int r = 0; r < 6; ++r)
                *(float4*)&qkvh[ocg * 6 + r][px4] =
                    make_float4(acc[r][0], acc[r][1], acc[r][2], acc[r][3]);
        }
        __syncthreads();

        // ---- dwconv 3x3 -> qt/kt/vt [32][64 used of 68] ----
        #pragma unroll
        for (int i = 0; i < 12; ++i) {
            int f = tid + i * 512;                // 0..6143 = 3*32*64
            int p  = f >> 11;
            int ch = (f >> 6) & 31;
            int py = (f >> 3) & 7, pxx = f & 7;
            const float* w9 = wdw + (size_t)(p * C + h * DHEAD + ch) * 9;
            float s = 0.f;
            #pragma unroll
            for (int dy = 0; dy < 3; ++dy)
                #pragma unroll
                for (int dx = 0; dx < 3; ++dx)
                    s += qkvh[p * 32 + ch][(py + dy) * 10 + (pxx + dx)] * w9[dy * 3 + dx];
            float* dst = (p == 0) ? &qt[0][0] : (p == 1) ? &kt[0][0] : &vt[0][0];
            dst[ch * 68 + py * 8 + pxx] = s;
        }
        __syncthreads();

        // ---- L2-normalize q,k rows (64 rows, 8 threads/row) ----
        {
            int row = tid >> 3;
            int sub = tid & 7;
            float* base = (row < 32) ? &qt[row][0] : &kt[row - 32][0];
            float ss = 0.f;
            #pragma unroll
            for (int e = 0; e < 8; ++e) { float v = base[sub * 8 + e]; ss += v * v; }
            ss += __shfl_xor(ss, 1);
            ss += __shfl_xor(ss, 2);
            ss += __shfl_xor(ss, 4);
            float sc = 1.f / fmaxf(sqrtf(ss), 1e-12f);
            #pragma unroll
            for (int e = 0; e < 8; ++e) base[sub * 8 + e] *= sc;
        }
        __syncthreads();

        // ---- logits [32][32] + softmax (16 threads/row, 2 cols each) ----
        float (*at)[33] = (float(*)[33])uni;
        {
            int i  = tid >> 4;                    // q-channel row
            int j2 = (tid & 15) * 2;              // 2 k-channel cols
            float a0 = 0.f, a1 = 0.f;
            #pragma unroll
            for (int e = 0; e < 64; e += 4) {
                float4 qv  = *(float4*)&qt[i][e];
                float4 k0v = *(float4*)&kt[j2][e];
                float4 k1v = *(float4*)&kt[j2 + 1][e];
                a0 += qv.x * k0v.x + qv.y * k0v.y + qv.z * k0v.z + qv.w * k0v.w;
                a1 += qv.x * k1v.x + qv.y * k1v.y + qv.z * k1v.z + qv.w * k1v.w;
            }
            float ts = temp[h];
            a0 *= ts; a1 *= ts;
            float m = fmaxf(a0, a1);
            m = fmaxf(m, __shfl_xor(m, 1));
            m = fmaxf(m, __shfl_xor(m, 2));
            m = fmaxf(m, __shfl_xor(m, 4));
            m = fmaxf(m, __shfl_xor(m, 8));
            float e0 = __expf(a0 - m), e1 = __expf(a1 - m);
            float s = e0 + e1;
            s += __shfl_xor(s, 1);
            s += __shfl_xor(s, 2);
            s += __shfl_xor(s, 4);
            s += __shfl_xor(s, 8);
            float inv = 1.f / s;
            at[i][j2]     = e0 * inv;
            at[i][j2 + 1] = e1 * inv;
        }
        __syncthreads();

        // ---- PV: out_h[32][64] = at @ vt; write to d_out (scratch) ----
        {
            int dd = tid >> 4;
            int p4 = (tid & 15) * 4;
            float o0 = 0, o1 = 0, o2 = 0, o3 = 0;
            #pragma unroll
            for (int e = 0; e < 32; ++e) {
                float a = at[dd][e];
                float4 v = *(float4*)&vt[e][p4];
                o0 += a * v.x; o1 += a * v.y; o2 += a * v.z; o3 += a * v.w;
            }
            int py = p4 >> 3, pxx = p4 & 7;
            float* dst = out + (size_t)b * C * NPIX +
                         (size_t)(h * DHEAD + dd) * NPIX +
                         (size_t)(wy * PS + py) * HW + wx * PS + pxx;
            *(float4*)dst = make_float4(o0, o1, o2, o3);
        }
        // next head's leading __syncthreads protects uni(at) and vt
    }

    // ---- proj: out[192][64] = Wp[192][192] @ attn_out (read back) ----
    float accp[6][4] = {};
    float (*bufWp)[36] = (float(*)[36])uni;             // [192][36] = 6912 f
    float (*ot)[68]    = (float(*)[68])(uni + 192 * 36);// [32][68]  = 2176 f
    const int pocg = tid >> 4;                          // 0..31 (6 oc each)
    const int pp4  = (tid & 15) * 4;                    // 0..60
    const float* outb = out + (size_t)b * C * NPIX;

    for (int k0 = 0; k0 < C; k0 += 32) {
        __syncthreads();   // prev phase done (incl. PV global writes drained)
        // stage Wp chunk: bufWp[oc][kk] = wproj[oc][k0+kk]
        #pragma unroll
        for (int i = 0; i < 12; ++i) {
            int f = tid + i * 512;                       // 0..6143
            int oc = f >> 5, kk = f & 31;
            bufWp[oc][kk] = wproj[(size_t)oc * C + k0 + kk];
        }
        // stage attn-out chunk [32 ic][64 px] from this block's d_out region
        {
            int icr = tid >> 4;                          // 0..31
            int pq  = tid & 15;
            int py = pq >> 1, pxx = (pq & 1) * 4;
            float4 v = *(const float4*)&outb[(size_t)(k0 + icr) * NPIX +
                                             (size_t)(wy * PS + py) * HW +
                                             wx * PS + pxx];
            *(float4*)&ot[icr][pq * 4] = v;
        }
        __syncthreads();
        #pragma unroll
        for (int kk = 0; kk < 32; kk += 4) {
            float4 xv0 = *(float4*)&ot[kk + 0][pp4];
            float4 xv1 = *(float4*)&ot[kk + 1][pp4];
            float4 xv2 = *(float4*)&ot[kk + 2][pp4];
            float4 xv3 = *(float4*)&ot[kk + 3][pp4];
            #pragma unroll
            for (int r = 0; r < 6; ++r) {
                float4 wv = *(float4*)&bufWp[pocg * 6 + r][kk];
                accp[r][0] += wv.x * xv0.x; accp[r][1] += wv.x * xv0.y;
                accp[r][2] += wv.x * xv0.z; accp[r][3] += wv.x * xv0.w;
                accp[r][0] += wv.y * xv1.x; accp[r][1] += wv.y * xv1.y;
                accp[r][2] += wv.y * xv1.z; accp[r][3] += wv.y * xv1.w;
                accp[r][0] += wv.z * xv2.x; accp[r][1] += wv.z * xv2.y;
                accp[r][2] += wv.z * xv2.z; accp[r][3] += wv.z * xv2.w;
                accp[r][0] += wv.w * xv3.x; accp[r][1] += wv.w * xv3.y;
                accp[r][2] += wv.w * xv3.z; accp[r][3] += wv.w * xv3.w;
            }
        }
    }

    // ---- final store (overwrites scratch region; LDS copies already staged) --
    {
        int py = pp4 >> 3, pxx = pp4 & 7;
        #pragma unroll
        for (int r = 0; r < 6; ++r) {
            float* dst = out + (size_t)b * C * NPIX +
                         (size_t)(pocg * 6 + r) * NPIX +
                         (size_t)(wy * PS + py) * HW + wx * PS + pxx;
            *(float4*)dst = make_float4(accp[r][0], accp[r][1], accp[r][2], accp[r][3]);
        }
    }
}

// -------------------------------------------------------------------------
extern "C" void kernel_launch(void* const* d_in, const int* in_sizes, int n_in,
                              void* d_out, int out_size, void* d_ws, size_t ws_size,
                              hipStream_t stream) {
    const float* x      = (const float*)d_in[0];
    const float* w_qkv  = (const float*)d_in[1];
    const float* w_dw   = (const float*)d_in[2];
    const float* w_proj = (const float*)d_in[3];
    const float* temp   = (const float*)d_in[4];
    float* out = (float*)d_out;
    (void)d_ws; (void)ws_size;  // deliberately unused: zero-workspace design

    fused_all<<<dim3(HWN * HWN, B), 512, 0, stream>>>(
        x, w_qkv, w_dw, w_proj, temp, out);
}

// Round 5
// 1019.348 us; speedup vs baseline: 1.7867x; 1.7867x over previous
//
#include <hip/hip_runtime.h>

// Problem constants
#define B_ 2
#define C_ 192
#define HEADS 6
#define DH 32
#define PS 8
#define HW 256
#define HWN 32
#define NPIX 65536

typedef short short8 __attribute__((ext_vector_type(8)));
typedef float f32x4 __attribute__((ext_vector_type(4)));

// Split fp32 into hi+lo bf16 (RNE). x ~= hi + lo with ~2^-17 relative error
// when recombined via 3 MFMA products (hihi + hilo + lohi).
__device__ inline void splitbf(float x, unsigned short& h, unsigned short& l) {
    unsigned u = __float_as_uint(x);
    unsigned hb = (u + 0x7fffu + ((u >> 16) & 1u)) & 0xffff0000u;
    h = (unsigned short)(hb >> 16);
    float lo = x - __uint_as_float(hb);
    unsigned ul = __float_as_uint(lo);
    l = (unsigned short)((ul + 0x7fffu + ((ul >> 16) & 1u)) >> 16);
}

// Fully-fused: qkv conv1x1 (MFMA) + dwconv3x3 + window channel-attention
// + proj conv1x1 (MFMA). One block per (window, batch), 512 threads.
// Zero d_ws usage; block's own d_out region is the attn-out scratch
// (pattern validated on HW by the R2 fp32 kernel).
__global__ __launch_bounds__(512, 2)
void fused_all(const float* __restrict__ x, const float* __restrict__ wqkv,
               const float* __restrict__ wdw, const float* __restrict__ wproj,
               const float* __restrict__ temp, float* __restrict__ out) {
    __shared__ __align__(16) union {
        struct {                             // phase 1: qkv GEMM staging
            unsigned short w_hi[576][40];    // rows padded to 80B: 2-way banks, b128-aligned
            unsigned short w_lo[576][40];
            unsigned short x_hi[128][40];    // [px][k] (B-operand, K-contig)
            unsigned short x_lo[128][40];
        } p1;                                // 112,640 B
        struct {                             // phase 2: per-head attention
            float qkvh[96][124];             // [3*32ch][10 rows x 12 (10 used)]
            float qt[32][68];
            float kt[32][68];
            float vt[32][68];
            float at[32][33];
        } p2;                                // 77,952 B
        struct {                             // phase 3: proj GEMM staging
            unsigned short wp_hi[192][40];
            unsigned short wp_lo[192][40];
            unsigned short o_hi[64][40];     // [px][k]
            unsigned short o_lo[64][40];
        } p3;                                // 40,960 B
    } sm;
    __shared__ int off[100];                 // halo px -> plane offset, -1 = pad

    const int tid = threadIdx.x;
    const int win = blockIdx.x;
    const int b   = blockIdx.y;
    const int wy = win >> 5, wx = win & 31;
    const int y0 = wy * PS - 1, x0 = wx * PS - 1;

    const int lane = tid & 63;
    const int w  = tid >> 6;     // wave 0..7
    const int wm = w >> 1;       // 0..3
    const int wn = w & 1;        // 0..1
    const int fr = lane & 15;    // frag row/col
    const int fg = lane >> 4;    // frag k-group / acc row group

    if (tid < 100) {
        int yy = tid / 10, xx = tid - yy * 10;
        int y = y0 + yy, xg = x0 + xx;
        off[tid] = ((unsigned)y < HW && (unsigned)xg < HW) ? y * HW + xg : -1;
    }

    const float* xb = x + (size_t)b * C_ * NPIX;

    // ================= Phase 1: qkv GEMM via hi/lo bf16 MFMA ==============
    // D[576 oc][128 px(100 used)] = Wqkv[576][192] @ xhalo[192][px]
    // wave (wm,wn): m-tiles 9wm..9wm+8, n-tiles 4wn..4wn+3
    f32x4 acc[9][4];
    #pragma unroll
    for (int m = 0; m < 9; ++m)
        #pragma unroll
        for (int n = 0; n < 4; ++n)
            acc[m][n] = f32x4{0.f, 0.f, 0.f, 0.f};

    for (int k0 = 0; k0 < C_; k0 += 32) {
        __syncthreads();
        // stage x chunk [32 k][128 px] -> transposed hi/lo planes [px][k]
        #pragma unroll
        for (int i = 0; i < 8; ++i) {
            int f = tid + i * 512;            // 4096
            int k = f >> 7, px = f & 127;
            float v = 0.f;
            if (px < 100) {
                int o = off[px];
                if (o >= 0) v = xb[(size_t)(k0 + k) * NPIX + o];
            }
            unsigned short hh, ll; splitbf(v, hh, ll);
            sm.p1.x_hi[px][k] = hh;
            sm.p1.x_lo[px][k] = ll;
        }
        // stage W chunk [576 oc][32 k] (vectorized float4 loads)
        #pragma unroll
        for (int i = 0; i < 9; ++i) {
            int f = tid + i * 512;            // 4608 quads
            int oc = f >> 3, k4 = (f & 7) * 4;
            float4 v = *(const float4*)&wqkv[(size_t)oc * C_ + k0 + k4];
            unsigned short h0, l0, h1, l1, h2, l2, h3, l3;
            splitbf(v.x, h0, l0); splitbf(v.y, h1, l1);
            splitbf(v.z, h2, l2); splitbf(v.w, h3, l3);
            unsigned* ph = (unsigned*)&sm.p1.w_hi[oc][0];
            unsigned* pl = (unsigned*)&sm.p1.w_lo[oc][0];
            ph[(k4 >> 1) + 0] = (unsigned)h0 | ((unsigned)h1 << 16);
            ph[(k4 >> 1) + 1] = (unsigned)h2 | ((unsigned)h3 << 16);
            pl[(k4 >> 1) + 0] = (unsigned)l0 | ((unsigned)l1 << 16);
            pl[(k4 >> 1) + 1] = (unsigned)l2 | ((unsigned)l3 << 16);
        }
        __syncthreads();

        short8 bh[4], bl[4];
        #pragma unroll
        for (int n = 0; n < 4; ++n) {
            int px = (wn * 4 + n) * 16 + fr;
            bh[n] = *(const short8*)&sm.p1.x_hi[px][fg * 8];
            bl[n] = *(const short8*)&sm.p1.x_lo[px][fg * 8];
        }
        #pragma unroll
        for (int m = 0; m < 9; ++m) {
            int row = (wm * 9 + m) * 16 + fr;
            short8 ah = *(const short8*)&sm.p1.w_hi[row][fg * 8];
            short8 al = *(const short8*)&sm.p1.w_lo[row][fg * 8];
            #pragma unroll
            for (int n = 0; n < 4; ++n) {
                acc[m][n] = __builtin_amdgcn_mfma_f32_16x16x32_bf16(al, bh[n], acc[m][n], 0, 0, 0);
                acc[m][n] = __builtin_amdgcn_mfma_f32_16x16x32_bf16(ah, bl[n], acc[m][n], 0, 0, 0);
                acc[m][n] = __builtin_amdgcn_mfma_f32_16x16x32_bf16(ah, bh[n], acc[m][n], 0, 0, 0);
            }
        }
    }
    __syncthreads();   // phase1 LDS reads done before p2 overwrites

    // ================= Phase 2: per-head dwconv + attention ===============
    for (int h = 0; h < HEADS; ++h) {
        // ---- dump this head's acc tiles -> qkvh [96][10x12] ----
        #pragma unroll
        for (int m = 0; m < 9; ++m) {
            int t = wm * 9 + m;                  // global 16-row tile
            int p  = (t * 16) / 192;             // q/k/v part
            int hh = ((t * 16) % 192) / 32;      // head of this tile
            if (hh == h) {
                int cbase = (t * 16) % 32;       // 0 or 16 within head
                #pragma unroll
                for (int j = 0; j < 4; ++j) {
                    int c = cbase + fg * 4 + j;
                    #pragma unroll
                    for (int n = 0; n < 4; ++n) {
                        int px = (wn * 4 + n) * 16 + fr;
                        if (px < 100) {
                            int yy = px / 10, xx = px - yy * 10;
                            sm.p2.qkvh[p * 32 + c][yy * 12 + xx] = acc[m][n][j];
                        }
                    }
                }
            }
        }
        __syncthreads();

        // ---- dwconv 3x3: vectorized row reads ----
        #pragma unroll
        for (int it = 0; it < 2; ++it) {
            int f = tid + it * 512;
            if (f < 768) {                        // (p, py, ch): ch fastest
                int p = f >> 8, rem = f & 255;
                int ch = rem & 31, py = (rem >> 5) & 7;
                const float* w9 = wdw + (size_t)(p * C_ + h * DH + ch) * 9;
                float w00 = w9[0], w01 = w9[1], w02 = w9[2];
                float w10 = w9[3], w11 = w9[4], w12 = w9[5];
                float w20 = w9[6], w21 = w9[7], w22 = w9[8];
                const float* base = &sm.p2.qkvh[p * 32 + ch][py * 12];
                float4 a0 = *(const float4*)(base);
                float4 a1 = *(const float4*)(base + 4);
                float2 a2 = *(const float2*)(base + 8);
                float4 b0 = *(const float4*)(base + 12);
                float4 b1 = *(const float4*)(base + 16);
                float2 b2 = *(const float2*)(base + 20);
                float4 c0 = *(const float4*)(base + 24);
                float4 c1 = *(const float4*)(base + 28);
                float2 c2 = *(const float2*)(base + 32);
                float r0[10] = {a0.x,a0.y,a0.z,a0.w,a1.x,a1.y,a1.z,a1.w,a2.x,a2.y};
                float r1[10] = {b0.x,b0.y,b0.z,b0.w,b1.x,b1.y,b1.z,b1.w,b2.x,b2.y};
                float r2[10] = {c0.x,c0.y,c0.z,c0.w,c1.x,c1.y,c1.z,c1.w,c2.x,c2.y};
                float* dst = ((p == 0) ? &sm.p2.qt[0][0] :
                              (p == 1) ? &sm.p2.kt[0][0] : &sm.p2.vt[0][0])
                             + ch * 68 + py * 8;
                #pragma unroll
                for (int px = 0; px < 8; ++px) {
                    dst[px] = r0[px] * w00 + r0[px+1] * w01 + r0[px+2] * w02
                            + r1[px] * w10 + r1[px+1] * w11 + r1[px+2] * w12
                            + r2[px] * w20 + r2[px+1] * w21 + r2[px+2] * w22;
                }
            }
        }
        __syncthreads();

        // ---- L2-normalize q,k rows (64 rows, 8 threads/row) ----
        {
            int row = tid >> 3, sub = tid & 7;
            float* base = (row < 32) ? &sm.p2.qt[row][0] : &sm.p2.kt[row - 32][0];
            float ss = 0.f;
            #pragma unroll
            for (int e = 0; e < 8; ++e) { float v = base[sub * 8 + e]; ss += v * v; }
            ss += __shfl_xor(ss, 1);
            ss += __shfl_xor(ss, 2);
            ss += __shfl_xor(ss, 4);
            float sc = 1.f / fmaxf(sqrtf(ss), 1e-12f);
            #pragma unroll
            for (int e = 0; e < 8; ++e) base[sub * 8 + e] *= sc;
        }
        __syncthreads();

        // ---- logits [32][32] + softmax ----
        {
            int i  = tid >> 4;
            int j2 = (tid & 15) * 2;
            float a0 = 0.f, a1 = 0.f;
            #pragma unroll
            for (int e = 0; e < 64; e += 4) {
                float4 qv  = *(const float4*)&sm.p2.qt[i][e];
                float4 k0v = *(const float4*)&sm.p2.kt[j2][e];
                float4 k1v = *(const float4*)&sm.p2.kt[j2 + 1][e];
                a0 += qv.x * k0v.x + qv.y * k0v.y + qv.z * k0v.z + qv.w * k0v.w;
                a1 += qv.x * k1v.x + qv.y * k1v.y + qv.z * k1v.z + qv.w * k1v.w;
            }
            float ts = temp[h];
            a0 *= ts; a1 *= ts;
            float m = fmaxf(a0, a1);
            m = fmaxf(m, __shfl_xor(m, 1));
            m = fmaxf(m, __shfl_xor(m, 2));
            m = fmaxf(m, __shfl_xor(m, 4));
            m = fmaxf(m, __shfl_xor(m, 8));
            float e0 = __expf(a0 - m), e1 = __expf(a1 - m);
            float s = e0 + e1;
            s += __shfl_xor(s, 1);
            s += __shfl_xor(s, 2);
            s += __shfl_xor(s, 4);
            s += __shfl_xor(s, 8);
            float inv = 1.f / s;
            sm.p2.at[i][j2]     = e0 * inv;
            sm.p2.at[i][j2 + 1] = e1 * inv;
        }
        __syncthreads();

        // ---- PV -> d_out scratch ----
        {
            int dd = tid >> 4;
            int p4 = (tid & 15) * 4;
            float o0 = 0, o1 = 0, o2 = 0, o3 = 0;
            #pragma unroll
            for (int e = 0; e < 32; ++e) {
                float a = sm.p2.at[dd][e];
                float4 v = *(const float4*)&sm.p2.vt[e][p4];
                o0 += a * v.x; o1 += a * v.y; o2 += a * v.z; o3 += a * v.w;
            }
            int py = p4 >> 3, pxx = p4 & 7;
            float* dst = out + (size_t)b * C_ * NPIX +
                         (size_t)(h * DH + dd) * NPIX +
                         (size_t)(wy * PS + py) * HW + wx * PS + pxx;
            *(float4*)dst = make_float4(o0, o1, o2, o3);
        }
        // next head's post-dump __syncthreads orders PV reads vs qt/kt/vt reuse
    }

    // ================= Phase 3: proj GEMM via hi/lo bf16 MFMA =============
    // D[192 oc][64 px] = Wp[192][192] @ attn_out[192][64]
    // wave (wm,wn): m-tiles 3wm..3wm+2, n-tiles 2wn..2wn+1
    f32x4 acc2[3][2];
    #pragma unroll
    for (int m = 0; m < 3; ++m)
        #pragma unroll
        for (int n = 0; n < 2; ++n)
            acc2[m][n] = f32x4{0.f, 0.f, 0.f, 0.f};

    const float* outb = out + (size_t)b * C_ * NPIX;

    for (int k0 = 0; k0 < C_; k0 += 32) {
        __syncthreads();   // p3 aliases p2; iter0 also drains PV writes pre-readback
        // stage Wp chunk [192][32]
        #pragma unroll
        for (int i = 0; i < 3; ++i) {
            int f = tid + i * 512;            // 1536 quads
            int oc = f >> 3, k4 = (f & 7) * 4;
            float4 v = *(const float4*)&wproj[(size_t)oc * C_ + k0 + k4];
            unsigned short h0, l0, h1, l1, h2, l2, h3, l3;
            splitbf(v.x, h0, l0); splitbf(v.y, h1, l1);
            splitbf(v.z, h2, l2); splitbf(v.w, h3, l3);
            unsigned* ph = (unsigned*)&sm.p3.wp_hi[oc][0];
            unsigned* pl = (unsigned*)&sm.p3.wp_lo[oc][0];
            ph[(k4 >> 1) + 0] = (unsigned)h0 | ((unsigned)h1 << 16);
            ph[(k4 >> 1) + 1] = (unsigned)h2 | ((unsigned)h3 << 16);
            pl[(k4 >> 1) + 0] = (unsigned)l0 | ((unsigned)l1 << 16);
            pl[(k4 >> 1) + 1] = (unsigned)l2 | ((unsigned)l3 << 16);
        }
        // stage attn-out chunk [32 ic][64 px] -> transposed hi/lo [px][k]
        {
            int ic = tid >> 4;
            int px4 = (tid & 15) * 4;
            int py = px4 >> 3, pxx = px4 & 7;
            float4 v = *(const float4*)&outb[(size_t)(k0 + ic) * NPIX +
                                             (size_t)(wy * PS + py) * HW +
                                             wx * PS + pxx];
            float vv[4] = {v.x, v.y, v.z, v.w};
            #pragma unroll
            for (int j = 0; j < 4; ++j) {
                unsigned short hh, ll; splitbf(vv[j], hh, ll);
                sm.p3.o_hi[px4 + j][ic] = hh;
                sm.p3.o_lo[px4 + j][ic] = ll;
            }
        }
        __syncthreads();

        short8 bh2[2], bl2[2];
        #pragma unroll
        for (int n = 0; n < 2; ++n) {
            int px = (wn * 2 + n) * 16 + fr;
            bh2[n] = *(const short8*)&sm.p3.o_hi[px][fg * 8];
            bl2[n] = *(const short8*)&sm.p3.o_lo[px][fg * 8];
        }
        #pragma unroll
        for (int m = 0; m < 3; ++m) {
            int row = (wm * 3 + m) * 16 + fr;
            short8 ah = *(const short8*)&sm.p3.wp_hi[row][fg * 8];
            short8 al = *(const short8*)&sm.p3.wp_lo[row][fg * 8];
            #pragma unroll
            for (int n = 0; n < 2; ++n) {
                acc2[m][n] = __builtin_amdgcn_mfma_f32_16x16x32_bf16(al, bh2[n], acc2[m][n], 0, 0, 0);
                acc2[m][n] = __builtin_amdgcn_mfma_f32_16x16x32_bf16(ah, bl2[n], acc2[m][n], 0, 0, 0);
                acc2[m][n] = __builtin_amdgcn_mfma_f32_16x16x32_bf16(ah, bh2[n], acc2[m][n], 0, 0, 0);
            }
        }
    }

    // ---- final store (overwrites scratch; all reads completed above) ----
    #pragma unroll
    for (int m = 0; m < 3; ++m)
        #pragma unroll
        for (int n = 0; n < 2; ++n)
            #pragma unroll
            for (int j = 0; j < 4; ++j) {
                int oc = (wm * 3 + m) * 16 + fg * 4 + j;
                int px = (wn * 2 + n) * 16 + fr;
                int py = px >> 3, pxx = px & 7;
                out[(size_t)b * C_ * NPIX + (size_t)oc * NPIX +
                    (size_t)(wy * PS + py) * HW + wx * PS + pxx] = acc2[m][n][j];
            }
}

// -------------------------------------------------------------------------
extern "C" void kernel_launch(void* const* d_in, const int* in_sizes, int n_in,
                              void* d_out, int out_size, void* d_ws, size_t ws_size,
                              hipStream_t stream) {
    const float* x      = (const float*)d_in[0];
    const float* w_qkv  = (const float*)d_in[1];
    const float* w_dw   = (const float*)d_in[2];
    const float* w_proj = (const float*)d_in[3];
    const float* temp   = (const float*)d_in[4];
    float* out = (float*)d_out;
    (void)d_ws; (void)ws_size;  // zero-workspace design

    fused_all<<<dim3(HWN * HWN, B_), 512, 0, stream>>>(
        x, w_qkv, w_dw, w_proj, temp, out);
}